// Round 1
// baseline (629.222 us; speedup 1.0000x reference)
//
#include <hip/hip_runtime.h>
#include <hip/hip_bf16.h>
#include <stdint.h>

// GQA attention block, MI355X gfx950.
// Pipeline: convert->bf16, QKV GEMM (MFMA), RoPE, V-transpose, flash attn, out GEMM.

typedef __attribute__((ext_vector_type(4))) float f32x4;
typedef __attribute__((ext_vector_type(8))) short sfrag;   // 8 bf16 bits
typedef __attribute__((ext_vector_type(8))) __bf16 bfrag;
typedef unsigned short u16;

__device__ __forceinline__ f32x4 mfma16(sfrag a, sfrag b, f32x4 c) {
  return __builtin_amdgcn_mfma_f32_16x16x32_bf16(
      __builtin_bit_cast(bfrag, a), __builtin_bit_cast(bfrag, b), c, 0, 0, 0);
}
__device__ __forceinline__ u16 f2b(float f) {
  return __builtin_bit_cast(u16, (__bf16)f);
}

#define GAS __attribute__((address_space(1)))
#define LAS __attribute__((address_space(3)))
__device__ __forceinline__ void gll16(const void* g, void* l) {
  __builtin_amdgcn_global_load_lds((GAS unsigned int*)g, (LAS unsigned int*)l, 16, 0, 0);
}

// ---------- f32 -> bf16 elementwise (x) ----------
__global__ __launch_bounds__(256) void k_convx(const float* __restrict__ X,
                                               u16* __restrict__ Y, int n) {
  int i = (blockIdx.x * 256 + threadIdx.x) * 4;
  if (i >= n) return;
  float4 v = *(const float4*)(X + i);
  *(ushort4*)(Y + i) = make_ushort4(f2b(v.x), f2b(v.y), f2b(v.z), f2b(v.w));
}

// ---------- W (2048 x N) f32 -> Wt (rowoff+N x 2048) bf16 transposed ----------
__global__ __launch_bounds__(256) void k_convT(const float* __restrict__ W,
                                               u16* __restrict__ Wt, int N, int rowoff) {
  __shared__ float tile[64][65];
  int n0 = blockIdx.x * 64, k0 = blockIdx.y * 64;
  #pragma unroll
  for (int p = 0; p < 16; ++p) {
    int idx = p * 256 + threadIdx.x;
    int kk = idx >> 6, nn = idx & 63;
    tile[kk][nn] = W[(size_t)(k0 + kk) * N + n0 + nn];
  }
  __syncthreads();
  #pragma unroll
  for (int p = 0; p < 16; ++p) {
    int idx = p * 256 + threadIdx.x;
    int nn = idx >> 6, kk = idx & 63;
    Wt[(size_t)(rowoff + n0 + nn) * 2048 + k0 + kk] = f2b(tile[kk][nn]);
  }
}

// ---------- GEMM: C(MxN f32) = A(MxK bf16) * Bt(NxK bf16)^T  (m97 structure) ----------
__global__ __launch_bounds__(256) void k_gemm(const u16* __restrict__ A,
                                              const u16* __restrict__ Bt,
                                              float* __restrict__ C, int N, int K) {
  __shared__ u16 As[128 * 64];
  __shared__ u16 Bs[128 * 64];
  const int tid = threadIdx.x;
  const int wave = tid >> 6, lane = tid & 63;
  const int l16 = lane & 15, l4 = lane >> 4;
  const int wm = (wave >> 1) * 64, wn = (wave & 1) * 64;
  const u16* Ab = A + (size_t)(blockIdx.y * 128) * K;
  const u16* Bb = Bt + (size_t)(blockIdx.x * 128) * K;
  const f32x4 zero = {0.f, 0.f, 0.f, 0.f};
  f32x4 acc[4][4];
  #pragma unroll
  for (int i = 0; i < 4; ++i)
    #pragma unroll
    for (int j = 0; j < 4; ++j) acc[i][j] = zero;

  for (int k0 = 0; k0 < K; k0 += 64) {
    #pragma unroll
    for (int j = 0; j < 4; ++j) {
      int c = j * 256 + tid;
      int row = c >> 3, cc = c & 7;
      int lbase = (j * 256 + wave * 64) * 8;   // wave-uniform LDS base (u16 units)
      gll16(Ab + (size_t)row * K + k0 + cc * 8, &As[lbase]);
      gll16(Bb + (size_t)row * K + k0 + cc * 8, &Bs[lbase]);
    }
    __syncthreads();   // drains vmcnt before barrier -> staged data visible
    #pragma unroll
    for (int f = 0; f < 2; ++f) {
      sfrag a[4], b[4];
      #pragma unroll
      for (int i = 0; i < 4; ++i)
        a[i] = *(const sfrag*)&As[(wm + i * 16 + l16) * 64 + f * 32 + l4 * 8];
      #pragma unroll
      for (int j = 0; j < 4; ++j)
        b[j] = *(const sfrag*)&Bs[(wn + j * 16 + l16) * 64 + f * 32 + l4 * 8];
      #pragma unroll
      for (int i = 0; i < 4; ++i)
        #pragma unroll
        for (int j = 0; j < 4; ++j)
          acc[i][j] = mfma16(a[i], b[j], acc[i][j]);
    }
    __syncthreads();
  }
  float* Cb = C + (size_t)(blockIdx.y * 128 + wm) * N + blockIdx.x * 128 + wn;
  #pragma unroll
  for (int i = 0; i < 4; ++i)
    #pragma unroll
    for (int j = 0; j < 4; ++j)
      #pragma unroll
      for (int r = 0; r < 4; ++r)
        Cb[(size_t)(i * 16 + l4 * 4 + r) * N + j * 16 + l16] = acc[i][j][r];
}

// ---------- RoPE + layout: QKV f32 (4096x3072) -> Qb bf16, Kb bf16, Kout/Vout f32 ----------
__global__ __launch_bounds__(256) void k_rope(const float* __restrict__ QKV,
                                              const int* __restrict__ sp,
                                              u16* __restrict__ Qb, u16* __restrict__ Kb,
                                              float* __restrict__ Kout,
                                              float* __restrict__ Vout) {
  const int row = blockIdx.x;          // b*2048 + t
  const int b = row >> 11, t = row & 2047;
  __shared__ float cs[32], sn[32];
  if (threadIdx.x < 32) {
    int j = threadIdx.x;
    float freq = powf(10000.0f, -(float)j * (1.0f / 32.0f));
    float ang = (float)(sp[0] + t) * freq;
    cs[j] = cosf(ang);
    sn[j] = sinf(ang);
  }
  __syncthreads();
  const float* src = QKV + (size_t)row * 3072;
  for (int p = threadIdx.x; p < 1280; p += 256) {   // 40 heads (32 Q + 8 K) x 32 pairs
    int head = p >> 5, j = p & 31;
    float c = cs[j], s = sn[j];
    float x1 = src[head * 64 + j], x2 = src[head * 64 + j + 32];
    float o1 = x1 * c - x2 * s, o2 = x1 * s + x2 * c;
    if (head < 32) {
      size_t o = ((size_t)(b * 32 + head) * 2048 + t) * 64 + j;
      Qb[o] = f2b(o1 * 0.125f);        // fold 1/sqrt(hd) into Q
      Qb[o + 32] = f2b(o2 * 0.125f);
    } else {
      int g = head - 32;
      size_t o = ((size_t)(b * 8 + g) * 2048 + t) * 64 + j;
      Kb[o] = f2b(o1);  Kb[o + 32] = f2b(o2);
      Kout[o] = o1;     Kout[o + 32] = o2;   // K^T output (B,G,T,hd)
    }
  }
  for (int p = threadIdx.x; p < 512; p += 256) {    // V copy-out (no rope)
    int g = p >> 6, d = p & 63;
    Vout[((size_t)(b * 8 + g) * 2048 + t) * 64 + d] = src[2560 + g * 64 + d];
  }
}

// ---------- V transpose: QKV cols 2560..3071 -> Vt bf16 (B,G,hd,T) ----------
__global__ __launch_bounds__(256) void k_vtrans(const float* __restrict__ QKV,
                                                u16* __restrict__ Vt) {
  __shared__ float tile[64][65];
  int t0 = blockIdx.x * 64;
  int bg = blockIdx.y, b = bg >> 3, g = bg & 7;
  #pragma unroll
  for (int p = 0; p < 16; ++p) {
    int idx = p * 256 + threadIdx.x;
    int tt = idx >> 6, d = idx & 63;
    tile[tt][d] = QKV[((size_t)(b * 2048 + t0 + tt)) * 3072 + 2560 + g * 64 + d];
  }
  __syncthreads();
  #pragma unroll
  for (int p = 0; p < 16; ++p) {
    int idx = p * 256 + threadIdx.x;
    int d = idx >> 6, tt = idx & 63;
    Vt[((size_t)(b * 8 + g) * 64 + d) * 2048 + t0 + tt] = f2b(tile[tt][d]);
  }
}

// ---------- Flash attention: 4 waves/block, 16 q-rows/wave, KV tiles of 32 ----------
__global__ __launch_bounds__(256) void k_attn(const u16* __restrict__ Qb,
                                              const u16* __restrict__ Kb,
                                              const u16* __restrict__ Vt,
                                              u16* __restrict__ attOut) {
  __shared__ u16 Plds[4][16][32];       // per-wave P transpose buffer
  const int bh = blockIdx.y, b = bh >> 5, h = bh & 31, g = h >> 2;
  const int wave = threadIdx.x >> 6, lane = threadIdx.x & 63;
  const int l16 = lane & 15, l4 = lane >> 4;
  const int qrow0 = blockIdx.x * 64 + wave * 16;
  const u16* Qp = Qb + (((size_t)b * 32 + h) * 2048 + qrow0 + l16) * 64 + l4 * 8;
  const sfrag q0 = *(const sfrag*)Qp;          // hd 0..31
  const sfrag q1 = *(const sfrag*)(Qp + 32);   // hd 32..63
  const u16* Kbase = Kb + ((size_t)b * 8 + g) * (2048 * 64);
  const u16* Vbase = Vt + ((size_t)b * 8 + g) * (64 * 2048) + (size_t)l16 * 2048 + l4 * 8;
  const f32x4 zero = {0.f, 0.f, 0.f, 0.f};
  f32x4 O[4] = {zero, zero, zero, zero};
  float m[4], l[4];
  #pragma unroll
  for (int r = 0; r < 4; ++r) { m[r] = -__builtin_inff(); l[r] = 0.f; }

  const int kv_end = qrow0 + 16;                 // causal bound (tiles of 32)
  for (int kv0 = 0; kv0 < kv_end; kv0 += 32) {
    const u16* Kp = Kbase + (size_t)(kv0 + l16) * 64 + l4 * 8;
    sfrag k00 = *(const sfrag*)Kp;               // kv chunk 0, hd 0..31
    sfrag k01 = *(const sfrag*)(Kp + 32);        // kv chunk 0, hd 32..63
    sfrag k10 = *(const sfrag*)(Kp + 1024);      // kv chunk 1 (16*64)
    sfrag k11 = *(const sfrag*)(Kp + 1056);
    f32x4 S0 = mfma16(q1, k01, mfma16(q0, k00, zero));
    f32x4 S1 = mfma16(q1, k11, mfma16(q0, k10, zero));
    #pragma unroll
    for (int r = 0; r < 4; ++r) {
      const int q = qrow0 + l4 * 4 + r;
      float s0 = (kv0 + l16 > q) ? -__builtin_inff() : S0[r];
      float s1 = (kv0 + 16 + l16 > q) ? -__builtin_inff() : S1[r];
      float mx = fmaxf(s0, s1);
      mx = fmaxf(mx, __shfl_xor(mx, 1));
      mx = fmaxf(mx, __shfl_xor(mx, 2));
      mx = fmaxf(mx, __shfl_xor(mx, 4));
      mx = fmaxf(mx, __shfl_xor(mx, 8));
      const float mnew = fmaxf(m[r], mx);        // finite: kv0 <= qrow0 always
      const float corr = __expf(m[r] - mnew);
      const float e0 = __expf(s0 - mnew);
      const float e1 = __expf(s1 - mnew);
      float rs = e0 + e1;
      rs += __shfl_xor(rs, 1);
      rs += __shfl_xor(rs, 2);
      rs += __shfl_xor(rs, 4);
      rs += __shfl_xor(rs, 8);
      m[r] = mnew;
      l[r] = l[r] * corr + rs;
      #pragma unroll
      for (int cc = 0; cc < 4; ++cc) O[cc][r] *= corr;
      Plds[wave][l4 * 4 + r][l16] = f2b(e0);
      Plds[wave][l4 * 4 + r][16 + l16] = f2b(e1);
    }
    // per-wave LDS ops are in-order; no barrier needed (private region per wave)
    const sfrag pa = *(const sfrag*)&Plds[wave][l16][l4 * 8];
    const u16* Vp = Vbase + kv0;
    #pragma unroll
    for (int cc = 0; cc < 4; ++cc)
      O[cc] = mfma16(pa, *(const sfrag*)(Vp + cc * (16 * 2048)), O[cc]);
  }
  #pragma unroll
  for (int r = 0; r < 4; ++r) {
    const float inv = 1.0f / l[r];
    size_t o = ((size_t)b * 2048 + qrow0 + l4 * 4 + r) * 2048 + h * 64;
    #pragma unroll
    for (int cc = 0; cc < 4; ++cc)
      attOut[o + cc * 16 + l16] = f2b(O[cc][r] * inv);
  }
}

extern "C" void kernel_launch(void* const* d_in, const int* in_sizes, int n_in,
                              void* d_out, int out_size, void* d_ws, size_t ws_size,
                              hipStream_t stream) {
  const float* x  = (const float*)d_in[0];
  const float* Wq = (const float*)d_in[1];
  const float* Wk = (const float*)d_in[2];
  const float* Wv = (const float*)d_in[3];
  const float* Wo = (const float*)d_in[4];
  const int* sp   = (const int*)d_in[5];
  float* y    = (float*)d_out;            // (B,T,2048) f32
  float* Kout = y + 8388608;              // (B,G,T,64) f32
  float* Vout = y + 10485760;             // (B,G,T,64) f32

  char* ws = (char*)d_ws;
  u16*   xb     = (u16*)(ws + 0);          // 16 MiB (reused as attOut later)
  u16*   Wqkvt  = (u16*)(ws + 16777216);   // 12 MiB  (3072 x 2048 bf16, transposed)
  u16*   Wot    = (u16*)(ws + 29360128);   // 8 MiB
  float* QKV    = (float*)(ws + 37748736); // 48 MiB  (4096 x 3072 f32)
  u16*   Qbuf   = (u16*)(ws + 88080384);   // 16 MiB  (B,H,T,hd) bf16, pre-scaled
  u16*   Kbuf   = (u16*)(ws + 104857600);  // 4 MiB   (B,G,T,hd) bf16
  u16*   Vt     = (u16*)(ws + 109051904);  // 4 MiB   (B,G,hd,T) bf16
  u16*   attOut = xb;                      // alias: xb dead after QKV GEMM

  k_convx<<<8192, 256, 0, stream>>>(x, xb, 8388608);
  k_convT<<<dim3(32, 32), 256, 0, stream>>>(Wq, Wqkvt, 2048, 0);
  k_convT<<<dim3(8, 32), 256, 0, stream>>>(Wk, Wqkvt, 512, 2048);
  k_convT<<<dim3(8, 32), 256, 0, stream>>>(Wv, Wqkvt, 512, 2560);
  k_convT<<<dim3(32, 32), 256, 0, stream>>>(Wo, Wot, 2048, 0);
  k_gemm<<<dim3(24, 32), 256, 0, stream>>>(xb, Wqkvt, QKV, 3072, 2048);
  k_rope<<<4096, 256, 0, stream>>>(QKV, sp, Qbuf, Kbuf, Kout, Vout);
  k_vtrans<<<dim3(32, 16), 256, 0, stream>>>(QKV, Vt);
  k_attn<<<dim3(32, 64), 256, 0, stream>>>(Qbuf, Kbuf, Vt, attOut);
  k_gemm<<<dim3(16, 32), 256, 0, stream>>>(attOut, Wot, y, 2048, 2048);
}

// Round 2
// 325.442 us; speedup vs baseline: 1.9334x; 1.9334x over previous
//
#include <hip/hip_runtime.h>
#include <hip/hip_bf16.h>
#include <stdint.h>

// GQA attention block, MI355X gfx950.
// Pipeline: convert->bf16, QKV GEMM (MFMA), RoPE, V-transpose, flash attn, out GEMM.
// R1: attention rewritten to swapped-QK^T 32x32 MFMA, in-register softmax, zero LDS.

typedef __attribute__((ext_vector_type(4))) float f32x4;
typedef __attribute__((ext_vector_type(16))) float f32x16;
typedef __attribute__((ext_vector_type(8))) short sfrag;   // 8 bf16 bits
typedef __attribute__((ext_vector_type(8))) __bf16 bfrag;
typedef __attribute__((ext_vector_type(4))) unsigned int u32x4;
typedef unsigned short u16;

__device__ __forceinline__ f32x4 mfma16(sfrag a, sfrag b, f32x4 c) {
  return __builtin_amdgcn_mfma_f32_16x16x32_bf16(
      __builtin_bit_cast(bfrag, a), __builtin_bit_cast(bfrag, b), c, 0, 0, 0);
}
__device__ __forceinline__ f32x16 mfma32(sfrag a, sfrag b, f32x16 c) {
  return __builtin_amdgcn_mfma_f32_32x32x16_bf16(
      __builtin_bit_cast(bfrag, a), __builtin_bit_cast(bfrag, b), c, 0, 0, 0);
}
__device__ __forceinline__ u16 f2b(float f) {
  return __builtin_bit_cast(u16, (__bf16)f);
}

#define GAS __attribute__((address_space(1)))
#define LAS __attribute__((address_space(3)))
__device__ __forceinline__ void gll16(const void* g, void* l) {
  __builtin_amdgcn_global_load_lds((GAS unsigned int*)g, (LAS unsigned int*)l, 16, 0, 0);
}

// ---------- f32 -> bf16 elementwise (x) ----------
__global__ __launch_bounds__(256) void k_convx(const float* __restrict__ X,
                                               u16* __restrict__ Y, int n) {
  int i = (blockIdx.x * 256 + threadIdx.x) * 4;
  if (i >= n) return;
  float4 v = *(const float4*)(X + i);
  *(ushort4*)(Y + i) = make_ushort4(f2b(v.x), f2b(v.y), f2b(v.z), f2b(v.w));
}

// ---------- W (2048 x N) f32 -> Wt (rowoff+N x 2048) bf16 transposed ----------
__global__ __launch_bounds__(256) void k_convT(const float* __restrict__ W,
                                               u16* __restrict__ Wt, int N, int rowoff) {
  __shared__ float tile[64][65];
  int n0 = blockIdx.x * 64, k0 = blockIdx.y * 64;
  #pragma unroll
  for (int p = 0; p < 16; ++p) {
    int idx = p * 256 + threadIdx.x;
    int kk = idx >> 6, nn = idx & 63;
    tile[kk][nn] = W[(size_t)(k0 + kk) * N + n0 + nn];
  }
  __syncthreads();
  #pragma unroll
  for (int p = 0; p < 16; ++p) {
    int idx = p * 256 + threadIdx.x;
    int nn = idx >> 6, kk = idx & 63;
    Wt[(size_t)(rowoff + n0 + nn) * 2048 + k0 + kk] = f2b(tile[kk][nn]);
  }
}

// ---------- GEMM: C(MxN f32) = A(MxK bf16) * Bt(NxK bf16)^T  (m97 structure) ----------
__global__ __launch_bounds__(256) void k_gemm(const u16* __restrict__ A,
                                              const u16* __restrict__ Bt,
                                              float* __restrict__ C, int N, int K) {
  __shared__ u16 As[128 * 64];
  __shared__ u16 Bs[128 * 64];
  const int tid = threadIdx.x;
  const int wave = tid >> 6, lane = tid & 63;
  const int l16 = lane & 15, l4 = lane >> 4;
  const int wm = (wave >> 1) * 64, wn = (wave & 1) * 64;
  const u16* Ab = A + (size_t)(blockIdx.y * 128) * K;
  const u16* Bb = Bt + (size_t)(blockIdx.x * 128) * K;
  const f32x4 zero = {0.f, 0.f, 0.f, 0.f};
  f32x4 acc[4][4];
  #pragma unroll
  for (int i = 0; i < 4; ++i)
    #pragma unroll
    for (int j = 0; j < 4; ++j) acc[i][j] = zero;

  for (int k0 = 0; k0 < K; k0 += 64) {
    #pragma unroll
    for (int j = 0; j < 4; ++j) {
      int c = j * 256 + tid;
      int row = c >> 3, cc = c & 7;
      int lbase = (j * 256 + wave * 64) * 8;   // wave-uniform LDS base (u16 units)
      gll16(Ab + (size_t)row * K + k0 + cc * 8, &As[lbase]);
      gll16(Bb + (size_t)row * K + k0 + cc * 8, &Bs[lbase]);
    }
    __syncthreads();
    #pragma unroll
    for (int f = 0; f < 2; ++f) {
      sfrag a[4], b[4];
      #pragma unroll
      for (int i = 0; i < 4; ++i)
        a[i] = *(const sfrag*)&As[(wm + i * 16 + l16) * 64 + f * 32 + l4 * 8];
      #pragma unroll
      for (int j = 0; j < 4; ++j)
        b[j] = *(const sfrag*)&Bs[(wn + j * 16 + l16) * 64 + f * 32 + l4 * 8];
      #pragma unroll
      for (int i = 0; i < 4; ++i)
        #pragma unroll
        for (int j = 0; j < 4; ++j)
          acc[i][j] = mfma16(a[i], b[j], acc[i][j]);
    }
    __syncthreads();
  }
  float* Cb = C + (size_t)(blockIdx.y * 128 + wm) * N + blockIdx.x * 128 + wn;
  #pragma unroll
  for (int i = 0; i < 4; ++i)
    #pragma unroll
    for (int j = 0; j < 4; ++j)
      #pragma unroll
      for (int r = 0; r < 4; ++r)
        Cb[(size_t)(i * 16 + l4 * 4 + r) * N + j * 16 + l16] = acc[i][j][r];
}

// ---------- RoPE + layout: QKV f32 (4096x3072) -> Qb bf16, Kb bf16, Kout/Vout f32 ----------
__global__ __launch_bounds__(256) void k_rope(const float* __restrict__ QKV,
                                              const int* __restrict__ sp,
                                              u16* __restrict__ Qb, u16* __restrict__ Kb,
                                              float* __restrict__ Kout,
                                              float* __restrict__ Vout) {
  const int row = blockIdx.x;          // b*2048 + t
  const int b = row >> 11, t = row & 2047;
  __shared__ float cs[32], sn[32];
  if (threadIdx.x < 32) {
    int j = threadIdx.x;
    float freq = powf(10000.0f, -(float)j * (1.0f / 32.0f));
    float ang = (float)(sp[0] + t) * freq;
    cs[j] = cosf(ang);
    sn[j] = sinf(ang);
  }
  __syncthreads();
  const float* src = QKV + (size_t)row * 3072;
  for (int p = threadIdx.x; p < 1280; p += 256) {   // 40 heads (32 Q + 8 K) x 32 pairs
    int head = p >> 5, j = p & 31;
    float c = cs[j], s = sn[j];
    float x1 = src[head * 64 + j], x2 = src[head * 64 + j + 32];
    float o1 = x1 * c - x2 * s, o2 = x1 * s + x2 * c;
    if (head < 32) {
      size_t o = ((size_t)(b * 32 + head) * 2048 + t) * 64 + j;
      Qb[o] = f2b(o1 * 0.125f);        // fold 1/sqrt(hd) into Q
      Qb[o + 32] = f2b(o2 * 0.125f);
    } else {
      int g = head - 32;
      size_t o = ((size_t)(b * 8 + g) * 2048 + t) * 64 + j;
      Kb[o] = f2b(o1);  Kb[o + 32] = f2b(o2);
      Kout[o] = o1;     Kout[o + 32] = o2;   // K^T output (B,G,T,hd)
    }
  }
  for (int p = threadIdx.x; p < 512; p += 256) {    // V copy-out (no rope)
    int g = p >> 6, d = p & 63;
    Vout[((size_t)(b * 8 + g) * 2048 + t) * 64 + d] = src[2560 + g * 64 + d];
  }
}

// ---------- V transpose: QKV cols 2560..3071 -> Vt bf16 (B,G,hd,T) ----------
__global__ __launch_bounds__(256) void k_vtrans(const float* __restrict__ QKV,
                                                u16* __restrict__ Vt) {
  __shared__ float tile[64][65];
  int t0 = blockIdx.x * 64;
  int bg = blockIdx.y, b = bg >> 3, g = bg & 7;
  #pragma unroll
  for (int p = 0; p < 16; ++p) {
    int idx = p * 256 + threadIdx.x;
    int tt = idx >> 6, d = idx & 63;
    tile[tt][d] = QKV[((size_t)(b * 2048 + t0 + tt)) * 3072 + 2560 + g * 64 + d];
  }
  __syncthreads();
  #pragma unroll
  for (int p = 0; p < 16; ++p) {
    int idx = p * 256 + threadIdx.x;
    int d = idx >> 6, tt = idx & 63;
    Vt[((size_t)(b * 8 + g) * 64 + d) * 2048 + t0 + tt] = f2b(tile[tt][d]);
  }
}

// ---------- Flash attention v2: swapped QK^T, 32x32 MFMA, in-register softmax ----------
// Per wave: 32 q-rows. S^T = mfma32(K_tile, Q^T): lane holds 16 kv-values of q-column
// (lane&31). Softmax reduce = in-reg tree + one shfl_xor(32). P feeds PV B-operand via
// 8 packed shfl_xor(32). O^T accumulated via mfma32(V^T, P^T). No LDS, no barriers.
template<bool MASKED>
__device__ __forceinline__ void attn_tile(const u16* __restrict__ Kbg,
                                          const u16* __restrict__ Vbg,
                                          int kv0, const sfrag* qf,
                                          int hi, int l31,
                                          f32x16& O0, f32x16& O1,
                                          float& m, float& l) {
  // ---- S^T tile: 4 MFMAs over hd=64 ----
  const u16* Kp = Kbg + (size_t)(kv0 + l31) * 64 + hi * 8;
  f32x16 S = {};
  #pragma unroll
  for (int ks = 0; ks < 4; ++ks)
    S = mfma32(*(const sfrag*)(Kp + ks * 16), qf[ks], S);

  // ---- mask + row max (per lane: 16 kv of one q-column) ----
  float sv[16];
  #pragma unroll
  for (int r = 0; r < 16; ++r) {
    float s = S[r];
    if (MASKED) {
      int kvo = (r & 3) + 8 * (r >> 2) + 4 * hi;   // kv offset within tile
      if (kvo > l31) s = -__builtin_inff();        // kv > q
    }
    sv[r] = s;
  }
  float t8[8];
  #pragma unroll
  for (int j = 0; j < 8; ++j) t8[j] = fmaxf(sv[j], sv[j + 8]);
  #pragma unroll
  for (int j = 0; j < 4; ++j) t8[j] = fmaxf(t8[j], t8[j + 4]);
  float mx = fmaxf(fmaxf(t8[0], t8[1]), fmaxf(t8[2], t8[3]));
  mx = fmaxf(mx, __shfl_xor(mx, 32));
  const float mnew = fmaxf(m, mx);
  const float corr = __expf(m - mnew);

  // ---- P = exp(S - mnew), row sum ----
  float p[16];
  #pragma unroll
  for (int r = 0; r < 16; ++r) p[r] = __expf(sv[r] - mnew);
  float s8[8];
  #pragma unroll
  for (int j = 0; j < 8; ++j) s8[j] = p[j] + p[j + 8];
  #pragma unroll
  for (int j = 0; j < 4; ++j) s8[j] = s8[j] + s8[j + 4];
  float rs = (s8[0] + s8[1]) + (s8[2] + s8[3]);
  rs += __shfl_xor(rs, 32);
  m = mnew;
  l = l * corr + rs;
  O0 *= corr;
  O1 *= corr;

  // ---- P -> bf16, exchange halves so each lane owns a contiguous 8-kv B-fragment ----
  unsigned w[8];
  #pragma unroll
  for (int j = 0; j < 8; ++j)
    w[j] = (unsigned)f2b(p[2 * j]) | ((unsigned)f2b(p[2 * j + 1]) << 16);
  unsigned pw[8];
  #pragma unroll
  for (int j = 0; j < 8; ++j) pw[j] = __shfl_xor(w[j], 32);
  // kv(reg r, hi) = (r&3)+8*(r>>2)+4*hi ; B-frag ks needs kv = ks*16 + hi*8 + [0..7]
  u32x4 f0 = (hi == 0) ? u32x4{w[0], w[1], pw[0], pw[1]}
                       : u32x4{pw[2], pw[3], w[2], w[3]};
  u32x4 f1 = (hi == 0) ? u32x4{w[4], w[5], pw[4], pw[5]}
                       : u32x4{pw[6], pw[7], w[6], w[7]};

  // ---- PV: O^T[d][q] += V^T[d][kv] * P^T[kv][q] ----
  const u16* Vp = Vbg + (size_t)l31 * 2048 + kv0 + hi * 8;
  const sfrag pf0 = __builtin_bit_cast(sfrag, f0);
  const sfrag pf1 = __builtin_bit_cast(sfrag, f1);
  O0 = mfma32(*(const sfrag*)(Vp), pf0, O0);
  O0 = mfma32(*(const sfrag*)(Vp + 16), pf1, O0);
  O1 = mfma32(*(const sfrag*)(Vp + 32 * 2048), pf0, O1);
  O1 = mfma32(*(const sfrag*)(Vp + 32 * 2048 + 16), pf1, O1);
}

__global__ __launch_bounds__(256) void k_attn2(const u16* __restrict__ Qb,
                                               const u16* __restrict__ Kb,
                                               const u16* __restrict__ Vt,
                                               u16* __restrict__ attOut) {
  const int bid = blockIdx.x;                 // 1024 blocks
  const int qg = 15 - (bid >> 6);             // heavy q-groups launch first
  const int bh = bid & 63;
  const int b = bh >> 5, h = bh & 31, g = h >> 2;
  const int wave = threadIdx.x >> 6, lane = threadIdx.x & 63;
  const int hi = lane >> 5, l31 = lane & 31;
  const int qrow0 = (qg * 4 + wave) * 32;

  const u16* Qp = Qb + (((size_t)b * 32 + h) * 2048 + qrow0 + l31) * 64 + hi * 8;
  sfrag qf[4];
  #pragma unroll
  for (int ks = 0; ks < 4; ++ks) qf[ks] = *(const sfrag*)(Qp + ks * 16);

  const u16* Kbg = Kb + ((size_t)b * 8 + g) * (2048 * 64);
  const u16* Vbg = Vt + ((size_t)b * 8 + g) * (64 * 2048);

  f32x16 O0 = {}, O1 = {};
  float m = -__builtin_inff(), l = 0.f;
  for (int kv0 = 0; kv0 < qrow0; kv0 += 32)
    attn_tile<false>(Kbg, Vbg, kv0, qf, hi, l31, O0, O1, m, l);
  attn_tile<true>(Kbg, Vbg, qrow0, qf, hi, l31, O0, O1, m, l);

  const float inv = 1.0f / l;
  const size_t orow = ((size_t)b * 2048 + qrow0 + l31) * 2048 + h * 64;
  #pragma unroll
  for (int dt = 0; dt < 2; ++dt) {
    const f32x16& O = dt ? O1 : O0;
    #pragma unroll
    for (int k = 0; k < 4; ++k) {
      ushort4 o;
      o.x = f2b(O[4 * k + 0] * inv);
      o.y = f2b(O[4 * k + 1] * inv);
      o.z = f2b(O[4 * k + 2] * inv);
      o.w = f2b(O[4 * k + 3] * inv);
      *(ushort4*)&attOut[orow + dt * 32 + 8 * k + 4 * hi] = o;
    }
  }
}

extern "C" void kernel_launch(void* const* d_in, const int* in_sizes, int n_in,
                              void* d_out, int out_size, void* d_ws, size_t ws_size,
                              hipStream_t stream) {
  const float* x  = (const float*)d_in[0];
  const float* Wq = (const float*)d_in[1];
  const float* Wk = (const float*)d_in[2];
  const float* Wv = (const float*)d_in[3];
  const float* Wo = (const float*)d_in[4];
  const int* sp   = (const int*)d_in[5];
  float* y    = (float*)d_out;            // (B,T,2048) f32
  float* Kout = y + 8388608;              // (B,G,T,64) f32
  float* Vout = y + 10485760;             // (B,G,T,64) f32

  char* ws = (char*)d_ws;
  u16*   xb     = (u16*)(ws + 0);          // 16 MiB (reused as attOut later)
  u16*   Wqkvt  = (u16*)(ws + 16777216);   // 12 MiB  (3072 x 2048 bf16, transposed)
  u16*   Wot    = (u16*)(ws + 29360128);   // 8 MiB
  float* QKV    = (float*)(ws + 37748736); // 48 MiB  (4096 x 3072 f32)
  u16*   Qbuf   = (u16*)(ws + 88080384);   // 16 MiB  (B,H,T,hd) bf16, pre-scaled
  u16*   Kbuf   = (u16*)(ws + 104857600);  // 4 MiB   (B,G,T,hd) bf16
  u16*   Vt     = (u16*)(ws + 109051904);  // 4 MiB   (B,G,hd,T) bf16
  u16*   attOut = xb;                      // alias: xb dead after QKV GEMM

  k_convx<<<8192, 256, 0, stream>>>(x, xb, 8388608);
  k_convT<<<dim3(32, 32), 256, 0, stream>>>(Wq, Wqkvt, 2048, 0);
  k_convT<<<dim3(8, 32), 256, 0, stream>>>(Wk, Wqkvt, 512, 2048);
  k_convT<<<dim3(8, 32), 256, 0, stream>>>(Wv, Wqkvt, 512, 2560);
  k_convT<<<dim3(32, 32), 256, 0, stream>>>(Wo, Wot, 2048, 0);
  k_gemm<<<dim3(24, 32), 256, 0, stream>>>(xb, Wqkvt, QKV, 3072, 2048);
  k_rope<<<4096, 256, 0, stream>>>(QKV, sp, Qbuf, Kbuf, Kout, Vout);
  k_vtrans<<<dim3(32, 16), 256, 0, stream>>>(QKV, Vt);
  k_attn2<<<1024, 256, 0, stream>>>(Qbuf, Kbuf, Vt, attOut);
  k_gemm<<<dim3(16, 32), 256, 0, stream>>>(attOut, Wot, y, 2048, 2048);
}

// Round 3
// 315.952 us; speedup vs baseline: 1.9915x; 1.0300x over previous
//
#include <hip/hip_runtime.h>
#include <hip/hip_bf16.h>
#include <stdint.h>

// GQA attention block, MI355X gfx950.
// Pipeline: convert->bf16, QKV GEMM (MFMA), RoPE, V-transpose, flash attn, out GEMM.
// R1: attention: swapped-QK^T 32x32 MFMA, in-register softmax, zero LDS.
// R2: attention: KVBLK=64, 1-wave balanced blocks, defer-max, log2-domain, setprio.

typedef __attribute__((ext_vector_type(4))) float f32x4;
typedef __attribute__((ext_vector_type(16))) float f32x16;
typedef __attribute__((ext_vector_type(8))) short sfrag;   // 8 bf16 bits
typedef __attribute__((ext_vector_type(8))) __bf16 bfrag;
typedef __attribute__((ext_vector_type(4))) unsigned int u32x4;
typedef unsigned short u16;

__device__ __forceinline__ f32x4 mfma16(sfrag a, sfrag b, f32x4 c) {
  return __builtin_amdgcn_mfma_f32_16x16x32_bf16(
      __builtin_bit_cast(bfrag, a), __builtin_bit_cast(bfrag, b), c, 0, 0, 0);
}
__device__ __forceinline__ f32x16 mfma32(sfrag a, sfrag b, f32x16 c) {
  return __builtin_amdgcn_mfma_f32_32x32x16_bf16(
      __builtin_bit_cast(bfrag, a), __builtin_bit_cast(bfrag, b), c, 0, 0, 0);
}
__device__ __forceinline__ u16 f2b(float f) {
  return __builtin_bit_cast(u16, (__bf16)f);
}
__device__ __forceinline__ unsigned pack2(float a, float b) {
  return (unsigned)f2b(a) | ((unsigned)f2b(b) << 16);
}

#define GAS __attribute__((address_space(1)))
#define LAS __attribute__((address_space(3)))
__device__ __forceinline__ void gll16(const void* g, void* l) {
  __builtin_amdgcn_global_load_lds((GAS unsigned int*)g, (LAS unsigned int*)l, 16, 0, 0);
}

// ---------- f32 -> bf16 elementwise (x) ----------
__global__ __launch_bounds__(256) void k_convx(const float* __restrict__ X,
                                               u16* __restrict__ Y, int n) {
  int i = (blockIdx.x * 256 + threadIdx.x) * 4;
  if (i >= n) return;
  float4 v = *(const float4*)(X + i);
  *(ushort4*)(Y + i) = make_ushort4(f2b(v.x), f2b(v.y), f2b(v.z), f2b(v.w));
}

// ---------- W (2048 x N) f32 -> Wt (rowoff+N x 2048) bf16 transposed ----------
__global__ __launch_bounds__(256) void k_convT(const float* __restrict__ W,
                                               u16* __restrict__ Wt, int N, int rowoff) {
  __shared__ float tile[64][65];
  int n0 = blockIdx.x * 64, k0 = blockIdx.y * 64;
  #pragma unroll
  for (int p = 0; p < 16; ++p) {
    int idx = p * 256 + threadIdx.x;
    int kk = idx >> 6, nn = idx & 63;
    tile[kk][nn] = W[(size_t)(k0 + kk) * N + n0 + nn];
  }
  __syncthreads();
  #pragma unroll
  for (int p = 0; p < 16; ++p) {
    int idx = p * 256 + threadIdx.x;
    int nn = idx >> 6, kk = idx & 63;
    Wt[(size_t)(rowoff + n0 + nn) * 2048 + k0 + kk] = f2b(tile[kk][nn]);
  }
}

// ---------- GEMM: C(MxN f32) = A(MxK bf16) * Bt(NxK bf16)^T  (m97 structure) ----------
__global__ __launch_bounds__(256) void k_gemm(const u16* __restrict__ A,
                                              const u16* __restrict__ Bt,
                                              float* __restrict__ C, int N, int K) {
  __shared__ u16 As[128 * 64];
  __shared__ u16 Bs[128 * 64];
  const int tid = threadIdx.x;
  const int wave = tid >> 6, lane = tid & 63;
  const int l16 = lane & 15, l4 = lane >> 4;
  const int wm = (wave >> 1) * 64, wn = (wave & 1) * 64;
  const u16* Ab = A + (size_t)(blockIdx.y * 128) * K;
  const u16* Bb = Bt + (size_t)(blockIdx.x * 128) * K;
  const f32x4 zero = {0.f, 0.f, 0.f, 0.f};
  f32x4 acc[4][4];
  #pragma unroll
  for (int i = 0; i < 4; ++i)
    #pragma unroll
    for (int j = 0; j < 4; ++j) acc[i][j] = zero;

  for (int k0 = 0; k0 < K; k0 += 64) {
    #pragma unroll
    for (int j = 0; j < 4; ++j) {
      int c = j * 256 + tid;
      int row = c >> 3, cc = c & 7;
      int lbase = (j * 256 + wave * 64) * 8;   // wave-uniform LDS base (u16 units)
      gll16(Ab + (size_t)row * K + k0 + cc * 8, &As[lbase]);
      gll16(Bb + (size_t)row * K + k0 + cc * 8, &Bs[lbase]);
    }
    __syncthreads();
    #pragma unroll
    for (int f = 0; f < 2; ++f) {
      sfrag a[4], b[4];
      #pragma unroll
      for (int i = 0; i < 4; ++i)
        a[i] = *(const sfrag*)&As[(wm + i * 16 + l16) * 64 + f * 32 + l4 * 8];
      #pragma unroll
      for (int j = 0; j < 4; ++j)
        b[j] = *(const sfrag*)&Bs[(wn + j * 16 + l16) * 64 + f * 32 + l4 * 8];
      #pragma unroll
      for (int i = 0; i < 4; ++i)
        #pragma unroll
        for (int j = 0; j < 4; ++j)
          acc[i][j] = mfma16(a[i], b[j], acc[i][j]);
    }
    __syncthreads();
  }
  float* Cb = C + (size_t)(blockIdx.y * 128 + wm) * N + blockIdx.x * 128 + wn;
  #pragma unroll
  for (int i = 0; i < 4; ++i)
    #pragma unroll
    for (int j = 0; j < 4; ++j)
      #pragma unroll
      for (int r = 0; r < 4; ++r)
        Cb[(size_t)(i * 16 + l4 * 4 + r) * N + j * 16 + l16] = acc[i][j][r];
}

// ---------- RoPE + layout: QKV f32 (4096x3072) -> Qb bf16, Kb bf16, Kout/Vout f32 ----------
// Q pre-scale folds 1/sqrt(hd) AND log2(e) (softmax runs in log2 domain).
__global__ __launch_bounds__(256) void k_rope(const float* __restrict__ QKV,
                                              const int* __restrict__ sp,
                                              u16* __restrict__ Qb, u16* __restrict__ Kb,
                                              float* __restrict__ Kout,
                                              float* __restrict__ Vout) {
  const int row = blockIdx.x;          // b*2048 + t
  const int b = row >> 11, t = row & 2047;
  __shared__ float cs[32], sn[32];
  if (threadIdx.x < 32) {
    int j = threadIdx.x;
    float freq = powf(10000.0f, -(float)j * (1.0f / 32.0f));
    float ang = (float)(sp[0] + t) * freq;
    cs[j] = cosf(ang);
    sn[j] = sinf(ang);
  }
  __syncthreads();
  const float QSCALE = 0.125f * 1.44269504f;
  const float* src = QKV + (size_t)row * 3072;
  for (int p = threadIdx.x; p < 1280; p += 256) {   // 40 heads (32 Q + 8 K) x 32 pairs
    int head = p >> 5, j = p & 31;
    float c = cs[j], s = sn[j];
    float x1 = src[head * 64 + j], x2 = src[head * 64 + j + 32];
    float o1 = x1 * c - x2 * s, o2 = x1 * s + x2 * c;
    if (head < 32) {
      size_t o = ((size_t)(b * 32 + head) * 2048 + t) * 64 + j;
      Qb[o] = f2b(o1 * QSCALE);
      Qb[o + 32] = f2b(o2 * QSCALE);
    } else {
      int g = head - 32;
      size_t o = ((size_t)(b * 8 + g) * 2048 + t) * 64 + j;
      Kb[o] = f2b(o1);  Kb[o + 32] = f2b(o2);
      Kout[o] = o1;     Kout[o + 32] = o2;   // K^T output (B,G,T,hd)
    }
  }
  for (int p = threadIdx.x; p < 512; p += 256) {    // V copy-out (no rope)
    int g = p >> 6, d = p & 63;
    Vout[((size_t)(b * 8 + g) * 2048 + t) * 64 + d] = src[2560 + g * 64 + d];
  }
}

// ---------- V transpose: QKV cols 2560..3071 -> Vt bf16 (B,G,hd,T) ----------
__global__ __launch_bounds__(256) void k_vtrans(const float* __restrict__ QKV,
                                                u16* __restrict__ Vt) {
  __shared__ float tile[64][65];
  int t0 = blockIdx.x * 64;
  int bg = blockIdx.y, b = bg >> 3, g = bg & 7;
  #pragma unroll
  for (int p = 0; p < 16; ++p) {
    int idx = p * 256 + threadIdx.x;
    int tt = idx >> 6, d = idx & 63;
    tile[tt][d] = QKV[((size_t)(b * 2048 + t0 + tt)) * 3072 + 2560 + g * 64 + d];
  }
  __syncthreads();
  #pragma unroll
  for (int p = 0; p < 16; ++p) {
    int idx = p * 256 + threadIdx.x;
    int d = idx >> 6, tt = idx & 63;
    Vt[((size_t)(b * 8 + g) * 64 + d) * 2048 + t0 + tt] = f2b(tile[tt][d]);
  }
}

// ---------- Flash attention v3 helpers ----------
// PV for one 32-kv subtile: pack p->bf16, exchange halves via shfl_xor(32),
// feed as B-operand of mfma32(V^T, P^T). p[16] = this lane's 16 kv-values.
__device__ __forceinline__ void pv_sub(const float* p, const u16* __restrict__ Vp,
                                       int hi, f32x16& O0, f32x16& O1) {
  unsigned w[8], pw[8];
  #pragma unroll
  for (int j = 0; j < 8; ++j) w[j] = pack2(p[2 * j], p[2 * j + 1]);
  #pragma unroll
  for (int j = 0; j < 8; ++j) pw[j] = __shfl_xor(w[j], 32);
  u32x4 f0 = (hi == 0) ? u32x4{w[0], w[1], pw[0], pw[1]}
                       : u32x4{pw[2], pw[3], w[2], w[3]};
  u32x4 f1 = (hi == 0) ? u32x4{w[4], w[5], pw[4], pw[5]}
                       : u32x4{pw[6], pw[7], w[6], w[7]};
  const sfrag pf0 = __builtin_bit_cast(sfrag, f0);
  const sfrag pf1 = __builtin_bit_cast(sfrag, f1);
  __builtin_amdgcn_s_setprio(1);
  O0 = mfma32(*(const sfrag*)(Vp), pf0, O0);
  O0 = mfma32(*(const sfrag*)(Vp + 16), pf1, O0);
  O1 = mfma32(*(const sfrag*)(Vp + 32 * 2048), pf0, O1);
  O1 = mfma32(*(const sfrag*)(Vp + 32 * 2048 + 16), pf1, O1);
  __builtin_amdgcn_s_setprio(0);
}

// 64-kv unmasked tile: two independent S-MFMA chains, one softmax pass.
__device__ __forceinline__ void tile64(const u16* __restrict__ Kbg,
                                       const u16* __restrict__ Vbg,
                                       int kv0, const sfrag* qf, int hi, int l31,
                                       f32x16& O0, f32x16& O1, float& m, float& l) {
  const u16* Kp = Kbg + (size_t)(kv0 + l31) * 64 + hi * 8;
  f32x16 Sa = {}, Sb = {};
  __builtin_amdgcn_s_setprio(1);
  #pragma unroll
  for (int ks = 0; ks < 4; ++ks) {
    Sa = mfma32(*(const sfrag*)(Kp + ks * 16), qf[ks], Sa);
    Sb = mfma32(*(const sfrag*)(Kp + 32 * 64 + ks * 16), qf[ks], Sb);
  }
  __builtin_amdgcn_s_setprio(0);
  float p[32];
  #pragma unroll
  for (int r = 0; r < 16; ++r) { p[r] = Sa[r]; p[16 + r] = Sb[r]; }
  float t[16];
  #pragma unroll
  for (int j = 0; j < 16; ++j) t[j] = fmaxf(p[j], p[j + 16]);
  #pragma unroll
  for (int j = 0; j < 8; ++j) t[j] = fmaxf(t[j], t[j + 8]);
  #pragma unroll
  for (int j = 0; j < 4; ++j) t[j] = fmaxf(t[j], t[j + 4]);
  float mx = fmaxf(fmaxf(t[0], t[1]), fmaxf(t[2], t[3]));
  mx = fmaxf(mx, __shfl_xor(mx, 32));
  if (!__all(mx - m <= 12.0f)) {           // defer-max: rescale only on real growth
    const float mn = fmaxf(m, mx);
    const float c = __builtin_amdgcn_exp2f(m - mn);
    O0 *= c; O1 *= c; l *= c; m = mn;
  }
  #pragma unroll
  for (int r = 0; r < 32; ++r) p[r] = __builtin_amdgcn_exp2f(p[r] - m);
  float s[16];
  #pragma unroll
  for (int j = 0; j < 16; ++j) s[j] = p[j] + p[j + 16];
  #pragma unroll
  for (int j = 0; j < 8; ++j) s[j] = s[j] + s[j + 8];
  #pragma unroll
  for (int j = 0; j < 4; ++j) s[j] = s[j] + s[j + 4];
  float rs = (s[0] + s[1]) + (s[2] + s[3]);
  rs += __shfl_xor(rs, 32);
  l += rs;
  const u16* Vp = Vbg + (size_t)l31 * 2048 + kv0 + hi * 8;
  pv_sub(p, Vp, hi, O0, O1);
  pv_sub(p + 16, Vp + 32, hi, O0, O1);
}

// 32-kv tile (remainder / masked diagonal).
template<bool MASKED>
__device__ __forceinline__ void tile32(const u16* __restrict__ Kbg,
                                       const u16* __restrict__ Vbg,
                                       int kv0, const sfrag* qf, int hi, int l31,
                                       f32x16& O0, f32x16& O1, float& m, float& l) {
  const u16* Kp = Kbg + (size_t)(kv0 + l31) * 64 + hi * 8;
  f32x16 S = {};
  __builtin_amdgcn_s_setprio(1);
  #pragma unroll
  for (int ks = 0; ks < 4; ++ks)
    S = mfma32(*(const sfrag*)(Kp + ks * 16), qf[ks], S);
  __builtin_amdgcn_s_setprio(0);
  float p[16];
  #pragma unroll
  for (int r = 0; r < 16; ++r) {
    float s = S[r];
    if (MASKED) {
      int kvo = (r & 3) + 8 * (r >> 2) + 4 * hi;
      if (kvo > l31) s = -__builtin_inff();
    }
    p[r] = s;
  }
  float t[8];
  #pragma unroll
  for (int j = 0; j < 8; ++j) t[j] = fmaxf(p[j], p[j + 8]);
  #pragma unroll
  for (int j = 0; j < 4; ++j) t[j] = fmaxf(t[j], t[j + 4]);
  float mx = fmaxf(fmaxf(t[0], t[1]), fmaxf(t[2], t[3]));
  mx = fmaxf(mx, __shfl_xor(mx, 32));
  if (!__all(mx - m <= 12.0f)) {
    const float mn = fmaxf(m, mx);
    const float c = __builtin_amdgcn_exp2f(m - mn);
    O0 *= c; O1 *= c; l *= c; m = mn;
  }
  #pragma unroll
  for (int r = 0; r < 16; ++r) p[r] = __builtin_amdgcn_exp2f(p[r] - m);
  float s8[8];
  #pragma unroll
  for (int j = 0; j < 8; ++j) s8[j] = p[j] + p[j + 8];
  #pragma unroll
  for (int j = 0; j < 4; ++j) s8[j] = s8[j] + s8[j + 4];
  float rs = (s8[0] + s8[1]) + (s8[2] + s8[3]);
  rs += __shfl_xor(rs, 32);
  l += rs;
  const u16* Vp = Vbg + (size_t)l31 * 2048 + kv0 + hi * 8;
  pv_sub(p, Vp, hi, O0, O1);
}

// One wave per 32-row q-block; 4096 single-wave blocks, heavy-first for balance.
__global__ __launch_bounds__(64, 3) void k_attn3(const u16* __restrict__ Qb,
                                                 const u16* __restrict__ Kb,
                                                 const u16* __restrict__ Vt,
                                                 u16* __restrict__ attOut) {
  const int bid = blockIdx.x;                 // 4096 blocks
  const int qb = 63 - (bid >> 6);             // heavy q-blocks launch first
  const int bh = bid & 63;
  const int b = bh >> 5, h = bh & 31, g = h >> 2;
  const int lane = threadIdx.x;
  const int hi = lane >> 5, l31 = lane & 31;
  const int qrow0 = qb * 32;

  const u16* Qp = Qb + (((size_t)b * 32 + h) * 2048 + qrow0 + l31) * 64 + hi * 8;
  sfrag qf[4];
  #pragma unroll
  for (int ks = 0; ks < 4; ++ks) qf[ks] = *(const sfrag*)(Qp + ks * 16);

  const u16* Kbg = Kb + ((size_t)b * 8 + g) * (2048 * 64);
  const u16* Vbg = Vt + ((size_t)b * 8 + g) * (64 * 2048);

  f32x16 O0 = {}, O1 = {};
  float m = -__builtin_inff(), l = 0.f;
  int kv = 0;
  for (; kv + 64 <= qrow0; kv += 64)
    tile64(Kbg, Vbg, kv, qf, hi, l31, O0, O1, m, l);
  if (kv < qrow0) {
    tile32<false>(Kbg, Vbg, kv, qf, hi, l31, O0, O1, m, l);
    kv += 32;
  }
  tile32<true>(Kbg, Vbg, qrow0, qf, hi, l31, O0, O1, m, l);

  const float inv = 1.0f / l;
  const size_t orow = ((size_t)b * 2048 + qrow0 + l31) * 2048 + h * 64;
  #pragma unroll
  for (int dt = 0; dt < 2; ++dt) {
    const f32x16& O = dt ? O1 : O0;
    #pragma unroll
    for (int k = 0; k < 4; ++k) {
      ushort4 o;
      o.x = f2b(O[4 * k + 0] * inv);
      o.y = f2b(O[4 * k + 1] * inv);
      o.z = f2b(O[4 * k + 2] * inv);
      o.w = f2b(O[4 * k + 3] * inv);
      *(ushort4*)&attOut[orow + dt * 32 + 8 * k + 4 * hi] = o;
    }
  }
}

extern "C" void kernel_launch(void* const* d_in, const int* in_sizes, int n_in,
                              void* d_out, int out_size, void* d_ws, size_t ws_size,
                              hipStream_t stream) {
  const float* x  = (const float*)d_in[0];
  const float* Wq = (const float*)d_in[1];
  const float* Wk = (const float*)d_in[2];
  const float* Wv = (const float*)d_in[3];
  const float* Wo = (const float*)d_in[4];
  const int* sp   = (const int*)d_in[5];
  float* y    = (float*)d_out;            // (B,T,2048) f32
  float* Kout = y + 8388608;              // (B,G,T,64) f32
  float* Vout = y + 10485760;             // (B,G,T,64) f32

  char* ws = (char*)d_ws;
  u16*   xb     = (u16*)(ws + 0);          // 16 MiB (reused as attOut later)
  u16*   Wqkvt  = (u16*)(ws + 16777216);   // 12 MiB  (3072 x 2048 bf16, transposed)
  u16*   Wot    = (u16*)(ws + 29360128);   // 8 MiB
  float* QKV    = (float*)(ws + 37748736); // 48 MiB  (4096 x 3072 f32)
  u16*   Qbuf   = (u16*)(ws + 88080384);   // 16 MiB  (B,H,T,hd) bf16, pre-scaled
  u16*   Kbuf   = (u16*)(ws + 104857600);  // 4 MiB   (B,G,T,hd) bf16
  u16*   Vt     = (u16*)(ws + 109051904);  // 4 MiB   (B,G,hd,T) bf16
  u16*   attOut = xb;                      // alias: xb dead after QKV GEMM

  k_convx<<<8192, 256, 0, stream>>>(x, xb, 8388608);
  k_convT<<<dim3(32, 32), 256, 0, stream>>>(Wq, Wqkvt, 2048, 0);
  k_convT<<<dim3(8, 32), 256, 0, stream>>>(Wk, Wqkvt, 512, 2048);
  k_convT<<<dim3(8, 32), 256, 0, stream>>>(Wv, Wqkvt, 512, 2560);
  k_convT<<<dim3(32, 32), 256, 0, stream>>>(Wo, Wot, 2048, 0);
  k_gemm<<<dim3(24, 32), 256, 0, stream>>>(xb, Wqkvt, QKV, 3072, 2048);
  k_rope<<<4096, 256, 0, stream>>>(QKV, sp, Qbuf, Kbuf, Kout, Vout);
  k_vtrans<<<dim3(32, 16), 256, 0, stream>>>(QKV, Vt);
  k_attn3<<<4096, 64, 0, stream>>>(Qbuf, Kbuf, Vt, attOut);
  k_gemm<<<dim3(16, 32), 256, 0, stream>>>(attOut, Wot, y, 2048, 2048);
}